// Round 1
// baseline (320.354 us; speedup 1.0000x reference)
//
#include <hip/hip_runtime.h>
#include <math.h>

#define B_    32
#define H_    32
#define KVH_  8
#define D_    128
#define HID_  4096
#define TPB_  64
#define MB_   32
#define G_    4
#define RQKV  6144
#define KS_   8
#define NCH   8
#define SCALING 0.08838834764831845f

// ---------------- prep: hidden_q [B][HID] int -> hqT [HID][B] float ----------------
__global__ __launch_bounds__(256) void k_prep(const int* __restrict__ hq, float* __restrict__ hqT) {
  int gid = blockIdx.x * 256 + threadIdx.x;        // 131072
  int k = gid & (HID_ - 1);
  int bb = gid >> 12;
  hqT[(size_t)k * B_ + bb] = (float)hq[(size_t)bb * HID_ + k];
}

// ---------------- GEMM: Yp[ks][R][32] partial = W[R][4096] x XT[4096][32] ----------------
// block: 256 thr, 64-j tile (j = j0+lane), k-split: blockIdx.y (8) x wave (4) -> 128 k per wave
__global__ __launch_bounds__(256) void k_gemm(const int* __restrict__ W, const float* __restrict__ XT,
                                              float* __restrict__ Yp, int R) {
  int jt = blockIdx.x, ks = blockIdx.y;
  int j0 = jt * 64;
  int wave = __builtin_amdgcn_readfirstlane((int)(threadIdx.x >> 6));
  int lane = threadIdx.x & 63;
  __shared__ __align__(16) float smem[8448];       // WT[4][32][64] then la[4][64][33]
  float acc[32];
#pragma unroll
  for (int i = 0; i < 32; i++) acc[i] = 0.f;
  int kbase = ks * 512 + wave * 128;
  for (int kc = 0; kc < 128; kc += 32) {
    // stage W[j0..j0+63][kbase+kc .. +31] into transposed, XOR-swizzled LDS
#pragma unroll
    for (int r = 0; r < 8; r++) {
      int jj = r * 8 + (lane >> 3);
      int kq = (lane & 7) * 4;
      const int4 w4 = *(const int4*)&W[(size_t)(j0 + jj) * HID_ + kbase + kc + kq];
      smem[(wave * 32 + kq + 0) * 64 + (jj ^ ((kq + 0) & 31))] = (float)w4.x;
      smem[(wave * 32 + kq + 1) * 64 + (jj ^ ((kq + 1) & 31))] = (float)w4.y;
      smem[(wave * 32 + kq + 2) * 64 + (jj ^ ((kq + 2) & 31))] = (float)w4.z;
      smem[(wave * 32 + kq + 3) * 64 + (jj ^ ((kq + 3) & 31))] = (float)w4.w;
    }
#pragma unroll 4
    for (int k = 0; k < 32; k++) {
      float wv = smem[(wave * 32 + k) * 64 + (lane ^ (k & 31))];
      const float* xrow = &XT[(size_t)(kbase + kc + k) * 32];   // wave-uniform -> s_load
#pragma unroll
      for (int bb = 0; bb < 32; bb++) acc[bb] = fmaf(wv, xrow[bb], acc[bb]);
    }
  }
  __syncthreads();                                  // all waves done with WT
#pragma unroll
  for (int bb = 0; bb < 32; bb++) smem[(wave * 64 + lane) * 33 + bb] = acc[bb];
  __syncthreads();
  for (int i = threadIdx.x; i < 2048; i += 256) {
    int jl = i >> 5, bb = i & 31;
    float v = smem[(0 * 64 + jl) * 33 + bb] + smem[(1 * 64 + jl) * 33 + bb] +
              smem[(2 * 64 + jl) * 33 + bb] + smem[(3 * 64 + jl) * 33 + bb];
    Yp[((size_t)ks * R + j0 + jl) * 32 + bb] = v;
  }
}

// ---------------- k1b: scales + RoPE + fresh k/v quant ----------------
__global__ __launch_bounds__(128) void k1b(const float* __restrict__ Yp, const float* __restrict__ hs,
                                           const float* __restrict__ wsc, const int* __restrict__ ctx,
                                           float* __restrict__ qrope, int* __restrict__ kqf,
                                           int* __restrict__ vqf, float* __restrict__ ksf,
                                           float* __restrict__ vsf) {
  int r = blockIdx.x;      // 0..47 (row-of-128 within 6144)
  int b = blockIdx.y;      // 0..31
  int d = threadIdx.x;     // 0..127
  int j = r * 128 + d;
  float v = 0.f;
#pragma unroll
  for (int ks = 0; ks < KS_; ks++) v += Yp[((size_t)ks * RQKV + j) * 32 + b];
  v *= hs[b] * wsc[j];
  __shared__ float x[128];
  __shared__ float red[2];
  x[d] = v;
  __syncthreads();
  int pos = ctx[b];
  float val;
  if (r < 40) {            // RoPE for q rows (0..31) and k rows (32..39)
    int i = d & 63;
    float f = powf(10000.f, -(float)i * (1.f / 64.f));
    float ang = (float)pos * f;
    float sv, cv;
    sincosf(ang, &sv, &cv);
    float xa = x[i], xb = x[i + 64];
    val = (d < 64) ? (xa * cv - xb * sv) : (xb * cv + xa * sv);
  } else {
    val = v;
  }
  if (r < 32) { qrope[((size_t)b * H_ + r) * D_ + d] = val; return; }
  // quantize (k or v row): per-row absmax over 128 threads (2 waves)
  float a = fabsf(val);
#pragma unroll
  for (int off = 32; off; off >>= 1) a = fmaxf(a, __shfl_xor(a, off));
  if ((d & 63) == 0) red[d >> 6] = a;
  __syncthreads();
  float mx = fmaxf(red[0], red[1]);
  float sc = fmaxf(mx, 1e-6f) * (1.f / 127.f);
  float qv = rintf(val / sc);
  qv = fminf(fmaxf(qv, -127.f), 127.f);
  int kvh = (r - 32) & 7;
  if (r < 40) {
    kqf[((size_t)b * KVH_ + kvh) * D_ + d] = (int)qv;
    if (d == 0) ksf[b * KVH_ + kvh] = sc;
  } else {
    vqf[((size_t)b * KVH_ + kvh) * D_ + d] = (int)qv;
    if (d == 0) vsf[b * KVH_ + kvh] = sc;
  }
}

// ---------------- k1c: fresh-token score q . k_fresh ----------------
__global__ __launch_bounds__(64) void k1c(const float* __restrict__ qrope, const int* __restrict__ kqf,
                                          const float* __restrict__ ksf, float* __restrict__ qkf) {
  int h = blockIdx.x, b = blockIdx.y, l = threadIdx.x;
  int kvh = h >> 2;
  const float* q = &qrope[((size_t)b * H_ + h) * D_];
  const int* kk = &kqf[((size_t)b * KVH_ + kvh) * D_];
  float s = q[l] * (float)kk[l] + q[l + 64] * (float)kk[l + 64];
#pragma unroll
  for (int off = 32; off; off >>= 1) s += __shfl_xor(s, off);
  if (l == 0) qkf[b * H_ + h] = s * ksf[b * KVH_ + kvh] * SCALING;
}

// ---------------- k2: flash-decoding attention over 256-token chunks ----------------
__global__ __launch_bounds__(256) void k2(const int* __restrict__ kvc, const float* __restrict__ kvs,
                                          const int* __restrict__ btab, const int* __restrict__ ctx,
                                          const float* __restrict__ qrope, const float* __restrict__ qkf,
                                          const int* __restrict__ vqf, const float* __restrict__ vsf,
                                          float* __restrict__ pm, float* __restrict__ pl,
                                          float* __restrict__ pacc) {
  int ch = blockIdx.x, kvh = blockIdx.y, b = blockIdx.z;
  int tid = threadIdx.x;
  int pos = ctx[b];
  int s0 = ch * 256;
  size_t pbase = ((size_t)(b * KVH_ + kvh) * NCH + ch) * G_;
  if (s0 > pos) {                                   // empty chunk
    if (tid < 4) { pm[pbase + tid] = -1e30f; pl[pbase + tid] = 0.f; }
    for (int i = tid; i < G_ * D_; i += 256) pacc[pbase * D_ + i] = 0.f;
    return;
  }
  __shared__ __align__(16) float qlds[512];
  __shared__ __align__(16) float plds[1024];
  __shared__ float rbuf[4][4];
  __shared__ int btl[32];
  for (int i = tid; i < 512; i += 256) qlds[i] = qrope[((size_t)b * H_ + kvh * G_) * D_ + i];
  if (tid < 32) btl[tid] = btab[b * MB_ + tid];
  __syncthreads();

  int s = s0 + tid;
  bool valid = (s <= pos);
  bool isfresh = (s == pos);
  float sc0 = 0.f, sc1 = 0.f, sc2 = 0.f, sc3 = 0.f;
  if (valid && !isfresh) {
    int blk = btl[s >> 6];
    int within = s & 63;
    const int* krow = &kvc[(((size_t)(blk * 2 + 0) * KVH_ + kvh) * TPB_ + within) * D_];
    float ksc = kvs[((size_t)(blk * 2 + 0) * KVH_ + kvh) * TPB_ + within];
#pragma unroll 4
    for (int d0 = 0; d0 < 128; d0 += 4) {
      int4 kk = *(const int4*)&krow[d0];
      float k0 = (float)kk.x, k1 = (float)kk.y, k2v = (float)kk.z, k3 = (float)kk.w;
      float4 q0 = *(const float4*)&qlds[0 * 128 + d0];
      float4 q1 = *(const float4*)&qlds[1 * 128 + d0];
      float4 q2 = *(const float4*)&qlds[2 * 128 + d0];
      float4 q3 = *(const float4*)&qlds[3 * 128 + d0];
      sc0 += q0.x * k0 + q0.y * k1 + q0.z * k2v + q0.w * k3;
      sc1 += q1.x * k0 + q1.y * k1 + q1.z * k2v + q1.w * k3;
      sc2 += q2.x * k0 + q2.y * k1 + q2.z * k2v + q2.w * k3;
      sc3 += q3.x * k0 + q3.y * k1 + q3.z * k2v + q3.w * k3;
    }
    float m = ksc * SCALING;
    sc0 *= m; sc1 *= m; sc2 *= m; sc3 *= m;
  } else if (isfresh) {
    sc0 = qkf[b * H_ + kvh * G_ + 0];
    sc1 = qkf[b * H_ + kvh * G_ + 1];
    sc2 = qkf[b * H_ + kvh * G_ + 2];
    sc3 = qkf[b * H_ + kvh * G_ + 3];
  }
  int wave = tid >> 6, lane = tid & 63;
  // chunk max per g
  float v0 = valid ? sc0 : -1e30f, v1 = valid ? sc1 : -1e30f;
  float v2 = valid ? sc2 : -1e30f, v3 = valid ? sc3 : -1e30f;
#pragma unroll
  for (int off = 32; off; off >>= 1) {
    v0 = fmaxf(v0, __shfl_xor(v0, off));
    v1 = fmaxf(v1, __shfl_xor(v1, off));
    v2 = fmaxf(v2, __shfl_xor(v2, off));
    v3 = fmaxf(v3, __shfl_xor(v3, off));
  }
  if (lane == 0) { rbuf[wave][0] = v0; rbuf[wave][1] = v1; rbuf[wave][2] = v2; rbuf[wave][3] = v3; }
  __syncthreads();
  float m0 = fmaxf(fmaxf(rbuf[0][0], rbuf[1][0]), fmaxf(rbuf[2][0], rbuf[3][0]));
  float m1 = fmaxf(fmaxf(rbuf[0][1], rbuf[1][1]), fmaxf(rbuf[2][1], rbuf[3][1]));
  float m2 = fmaxf(fmaxf(rbuf[0][2], rbuf[1][2]), fmaxf(rbuf[2][2], rbuf[3][2]));
  float m3 = fmaxf(fmaxf(rbuf[0][3], rbuf[1][3]), fmaxf(rbuf[2][3], rbuf[3][3]));
  float p0 = valid ? expf(sc0 - m0) : 0.f;
  float p1 = valid ? expf(sc1 - m1) : 0.f;
  float p2 = valid ? expf(sc2 - m2) : 0.f;
  float p3 = valid ? expf(sc3 - m3) : 0.f;
  float t0 = p0, t1 = p1, t2 = p2, t3 = p3;
#pragma unroll
  for (int off = 32; off; off >>= 1) {
    t0 += __shfl_xor(t0, off);
    t1 += __shfl_xor(t1, off);
    t2 += __shfl_xor(t2, off);
    t3 += __shfl_xor(t3, off);
  }
  __syncthreads();                                  // rbuf reuse
  if (lane == 0) { rbuf[wave][0] = t0; rbuf[wave][1] = t1; rbuf[wave][2] = t2; rbuf[wave][3] = t3; }
  __syncthreads();
  float l0 = rbuf[0][0] + rbuf[1][0] + rbuf[2][0] + rbuf[3][0];
  float l1 = rbuf[0][1] + rbuf[1][1] + rbuf[2][1] + rbuf[3][1];
  float l2 = rbuf[0][2] + rbuf[1][2] + rbuf[2][2] + rbuf[3][2];
  float l3 = rbuf[0][3] + rbuf[1][3] + rbuf[2][3] + rbuf[3][3];
  if (tid == 0) {
    pm[pbase + 0] = m0; pm[pbase + 1] = m1; pm[pbase + 2] = m2; pm[pbase + 3] = m3;
    pl[pbase + 0] = l0; pl[pbase + 1] = l1; pl[pbase + 2] = l2; pl[pbase + 3] = l3;
  }
  // pv multiplier = p * v_scale (fresh scale at s==pos), 0 if invalid
  float vsc = 0.f;
  if (valid) {
    if (isfresh) vsc = vsf[b * KVH_ + kvh];
    else {
      int blk = btl[s >> 6];
      vsc = kvs[((size_t)(blk * 2 + 1) * KVH_ + kvh) * TPB_ + (s & 63)];
    }
  }
  plds[tid * 4 + 0] = p0 * vsc;
  plds[tid * 4 + 1] = p1 * vsc;
  plds[tid * 4 + 2] = p2 * vsc;
  plds[tid * 4 + 3] = p3 * vsc;
  __syncthreads();
  // PV: d-per-lane (wave covers 32 d, halves split tokens)
  int nvalid = min(256, pos + 1 - s0);
  int dloc = (wave << 5) + (lane & 31);
  int half = lane >> 5;
  float a0 = 0.f, a1 = 0.f, a2 = 0.f, a3 = 0.f;
  for (int tt = half; tt < nvalid; tt += 2) {
    int s2 = s0 + tt;
    const int* vrow;
    if (s2 == pos) {
      vrow = &vqf[(size_t)(b * KVH_ + kvh) * D_];
    } else {
      int blk2 = btl[s2 >> 6];
      vrow = &kvc[(((size_t)(blk2 * 2 + 1) * KVH_ + kvh) * TPB_ + (s2 & 63)) * D_];
    }
    float vv = (float)vrow[dloc];
    float4 pp = *(const float4*)&plds[tt * 4];
    a0 = fmaf(pp.x, vv, a0);
    a1 = fmaf(pp.y, vv, a1);
    a2 = fmaf(pp.z, vv, a2);
    a3 = fmaf(pp.w, vv, a3);
  }
  a0 += __shfl_xor(a0, 32);
  a1 += __shfl_xor(a1, 32);
  a2 += __shfl_xor(a2, 32);
  a3 += __shfl_xor(a3, 32);
  if (half == 0) {
    float* pa = &pacc[pbase * D_];
    pa[0 * D_ + dloc] = a0;
    pa[1 * D_ + dloc] = a1;
    pa[2 * D_ + dloc] = a2;
    pa[3 * D_ + dloc] = a3;
  }
}

// ---------------- k3a: combine chunks + per-batch quantize ----------------
__global__ __launch_bounds__(256) void k3a(const float* __restrict__ pm, const float* __restrict__ pl,
                                           const float* __restrict__ pacc, float* __restrict__ aqT,
                                           float* __restrict__ asb) {
  int b = blockIdx.x;
  int tid = threadIdx.x;
  __shared__ float wch[32][8];
  __shared__ float invL[32];
  __shared__ float rbuf2[4];
  if (tid < 32) {
    int kvh = tid >> 2, g = tid & 3;
    float m[8], lv[8];
    float M = -1e30f;
#pragma unroll
    for (int ch = 0; ch < 8; ch++) {
      size_t pb = ((size_t)(b * KVH_ + kvh) * NCH + ch) * G_ + g;
      m[ch] = pm[pb];
      lv[ch] = pl[pb];
      M = fmaxf(M, m[ch]);
    }
    float L = 0.f;
#pragma unroll
    for (int ch = 0; ch < 8; ch++) {
      float w = expf(m[ch] - M);
      wch[tid][ch] = w;
      L += lv[ch] * w;
    }
    invL[tid] = 1.f / L;
  }
  __syncthreads();
  float vals[16];
  float amax = 0.f;
#pragma unroll
  for (int i = 0; i < 16; i++) {
    int j = i * 256 + tid;
    int h = j >> 7, d = j & 127;
    int kvh = h >> 2, g = h & 3;
    float v = 0.f;
#pragma unroll
    for (int ch = 0; ch < 8; ch++) {
      v += pacc[(((size_t)(b * KVH_ + kvh) * NCH + ch) * G_ + g) * D_ + d] * wch[h][ch];
    }
    v *= invL[h];
    vals[i] = v;
    amax = fmaxf(amax, fabsf(v));
  }
#pragma unroll
  for (int off = 32; off; off >>= 1) amax = fmaxf(amax, __shfl_xor(amax, off));
  if ((tid & 63) == 0) rbuf2[tid >> 6] = amax;
  __syncthreads();
  amax = fmaxf(fmaxf(rbuf2[0], rbuf2[1]), fmaxf(rbuf2[2], rbuf2[3]));
  float as = fmaxf(amax, 1e-6f) * (1.f / 127.f);
#pragma unroll
  for (int i = 0; i < 16; i++) {
    int j = i * 256 + tid;
    float qv = rintf(vals[i] / as);
    qv = fminf(fmaxf(qv, -127.f), 127.f);
    aqT[(size_t)j * 32 + b] = qv;                   // stored as float for GEMM
  }
  if (tid == 0) asb[b] = as;
}

// ---------------- k3c: reduce o-proj partials + final scales ----------------
__global__ __launch_bounds__(256) void k3c(const float* __restrict__ Yp, const float* __restrict__ asb,
                                           const float* __restrict__ owsc, float* __restrict__ out) {
  int gid = blockIdx.x * 256 + threadIdx.x;         // 131072
  int bb = gid & 31, i = gid >> 5;
  float v = 0.f;
#pragma unroll
  for (int ks = 0; ks < KS_; ks++) v += Yp[((size_t)ks * HID_ + i) * 32 + bb];
  out[(size_t)bb * HID_ + i] = v * asb[bb] * owsc[i];
}

extern "C" void kernel_launch(void* const* d_in, const int* in_sizes, int n_in,
                              void* d_out, int out_size, void* d_ws, size_t ws_size,
                              hipStream_t stream) {
  const int*   hq    = (const int*)d_in[0];
  const float* hs    = (const float*)d_in[1];
  const int*   qkvw  = (const int*)d_in[2];
  const float* qkvws = (const float*)d_in[3];
  const int*   ow    = (const int*)d_in[4];
  const float* owsc  = (const float*)d_in[5];
  const int*   kvc   = (const int*)d_in[6];
  const float* kvs   = (const float*)d_in[7];
  const int*   btab  = (const int*)d_in[8];
  const int*   ctx   = (const int*)d_in[9];
  float* out = (float*)d_out;

  char* ws = (char*)d_ws;
  float* hqT   = (float*)(ws);                 // 524288 B
  float* Yp    = (float*)(ws + 524288);        // 6291456 B (shared by both GEMMs)
  float* qrope = (float*)(ws + 6815744);       // 524288 B
  int*   kqf   = (int*)  (ws + 7340032);       // 131072 B
  int*   vqf   = (int*)  (ws + 7471104);       // 131072 B
  float* ksf   = (float*)(ws + 7602176);       // 1024 B
  float* vsf   = (float*)(ws + 7603200);       // 1024 B
  float* qkf   = (float*)(ws + 7604224);       // 4096 B
  float* pm    = (float*)(ws + 7608320);       // 32768 B
  float* pl    = (float*)(ws + 7641088);       // 32768 B
  float* pacc  = (float*)(ws + 7673856);       // 4194304 B
  float* aqT   = (float*)(ws + 11868160);      // 524288 B
  float* asb   = (float*)(ws + 12392448);      // 128 B

  k_prep<<<512, 256, 0, stream>>>(hq, hqT);
  k_gemm<<<dim3(RQKV / 64, KS_), 256, 0, stream>>>(qkvw, hqT, Yp, RQKV);
  k1b<<<dim3(48, 32), 128, 0, stream>>>(Yp, hs, qkvws, ctx, qrope, kqf, vqf, ksf, vsf);
  k1c<<<dim3(32, 32), 64, 0, stream>>>(qrope, kqf, ksf, qkf);
  k2<<<dim3(NCH, KVH_, B_), 256, 0, stream>>>(kvc, kvs, btab, ctx, qrope, qkf, vqf, vsf, pm, pl, pacc);
  k3a<<<32, 256, 0, stream>>>(pm, pl, pacc, aqT, asb);
  k_gemm<<<dim3(HID_ / 64, KS_), 256, 0, stream>>>(ow, aqT, Yp, HID_);
  k3c<<<512, 256, 0, stream>>>(Yp, asb, owsc, out);
}